// Round 3
// baseline (1461.424 us; speedup 1.0000x reference)
//
#include <hip/hip_runtime.h>
#include <math.h>

// CRF-RNN mean-field, MI355X.  seg:[4][21][4096] f32, W:[4][4096][4096] f32, wc:[21][21] f32.
// qVals_{t+1}[b,d,m] = seg[b,d,m] - sum_e wc[d,e] * (sum_n Q_t[b,e,n] * D[b,m,n]),
//   D = W / rowsum(W)  (precomputed ONCE as bf16 -> 134 MB, L3-resident),
//   Q_t = softmax_d(qVals_t) stored bf16, classes padded 21->24 with zeros.
//
// iter_k: 64-thr blocks, grid 4096 (4 waves/SIMD). Wave = 4 groups x 16 lanes.
// Groups share rows m0..m0+3, each group owns 6 classes. Per n-step (128 cols):
// 4 W uint4 loads (group-broadcast) + 6 Q uint4 loads = 10 loads, 24 acc VGPRs.
// Epilogue: 16-lane butterfly reduce, cross-group shfl gather, compat mix,
// seg-subtract, fused next-iter softmax (writes Q bf16) or final fp32 out.

#define DC 21
#define DCP 24
#define NN 4096
#define BS 4
#define CPG 6
#define RPW 4

typedef unsigned int u32;
typedef unsigned short u16;

__device__ __forceinline__ u16 f2bf(float f) {
    u32 u = __float_as_uint(f);
    u = u + 0x7fffu + ((u >> 16) & 1u);   // round-to-nearest-even
    return (u16)(u >> 16);
}
__device__ __forceinline__ float bflo(u32 u) { return __uint_as_float(u << 16); }
__device__ __forceinline__ float bfhi(u32 u) { return __uint_as_float(u & 0xffff0000u); }

// ---- one-time: rowsum + normalize + fp32->bf16 ----
__global__ __launch_bounds__(64) void prep_k(const float* __restrict__ W,
                                             u16* __restrict__ D) {
    const int m = blockIdx.x;            // b*4096 + row
    const int l = threadIdx.x;
    const float4* Wr = (const float4*)(W + (size_t)m * NN) + l;
    float4 v[16];
    float s = 0.f;
#pragma unroll
    for (int i = 0; i < 16; ++i) {
        v[i] = Wr[i * 64];
        s += (v[i].x + v[i].y) + (v[i].z + v[i].w);
    }
#pragma unroll
    for (int off = 1; off < 64; off <<= 1) s += __shfl_xor(s, off);
    const float inv = 1.f / s;
    u32* Dr = (u32*)(D + (size_t)m * NN);
#pragma unroll
    for (int i = 0; i < 16; ++i) {
        u32 p0 = (u32)f2bf(v[i].x * inv) | ((u32)f2bf(v[i].y * inv) << 16);
        u32 p1 = (u32)f2bf(v[i].z * inv) | ((u32)f2bf(v[i].w * inv) << 16);
        *(uint2*)(Dr + i * 128 + l * 2) = make_uint2(p0, p1);
    }
}

// ---- initial softmax: seg f32 -> Q bf16 (padded classes = 0) ----
__global__ __launch_bounds__(256) void softmax0_k(const float* __restrict__ x,
                                                  u16* __restrict__ q) {
    unsigned gid = blockIdx.x * 256u + threadIdx.x;
    unsigned b = gid >> 12, n = gid & 4095u;
    const float* xb = x + (size_t)b * DC * NN + n;
    float v[DC];
    float m = -1e30f;
#pragma unroll
    for (int d = 0; d < DC; ++d) { v[d] = xb[(size_t)d * NN]; m = fmaxf(m, v[d]); }
    float s = 0.f;
#pragma unroll
    for (int d = 0; d < DC; ++d) { v[d] = __expf(v[d] - m); s += v[d]; }
    float inv = 1.f / s;
    u16* qb = q + (size_t)b * DCP * NN + n;
#pragma unroll
    for (int d = 0; d < DC; ++d) qb[(size_t)d * NN] = f2bf(v[d] * inv);
#pragma unroll
    for (int d = DC; d < DCP; ++d) qb[(size_t)d * NN] = 0;
}

// ---- main iteration ----
__global__ __launch_bounds__(64, 4) void iter_k(const u16* __restrict__ Q,
                                                const u16* __restrict__ D,
                                                const float* __restrict__ wc,
                                                const float* __restrict__ seg,
                                                u16* __restrict__ qnext,
                                                float* __restrict__ out,
                                                int last) {
    const int lane = threadIdx.x;
    const int g = lane >> 4;
    const int l = lane & 15;
    const int b  = blockIdx.x >> 10;
    const int rt = blockIdx.x & 1023;
    const int m0 = rt * RPW;

    const uint4* Wp = (const uint4*)(D + ((size_t)b * NN + m0) * NN) + l;              // +r*512 +s*16
    const uint4* Qp = (const uint4*)(Q + (size_t)b * DCP * NN) + l + g * (CPG * 512);  // +j*512 +s*16

    float acc[RPW][CPG];
#pragma unroll
    for (int r = 0; r < RPW; ++r)
#pragma unroll
        for (int j = 0; j < CPG; ++j) acc[r][j] = 0.f;

#pragma unroll 2
    for (int s = 0; s < 32; ++s) {
        uint4 wv[RPW], qv[CPG];
#pragma unroll
        for (int r = 0; r < RPW; ++r) wv[r] = Wp[r * 512 + s * 16];
#pragma unroll
        for (int j = 0; j < CPG; ++j) qv[j] = Qp[j * 512 + s * 16];
#pragma unroll
        for (int p = 0; p < 4; ++p) {
            float wl[RPW], wh[RPW], ql[CPG], qh[CPG];
#pragma unroll
            for (int r = 0; r < RPW; ++r) {
                u32 u = (p == 0) ? wv[r].x : (p == 1) ? wv[r].y : (p == 2) ? wv[r].z : wv[r].w;
                wl[r] = bflo(u); wh[r] = bfhi(u);
            }
#pragma unroll
            for (int j = 0; j < CPG; ++j) {
                u32 u = (p == 0) ? qv[j].x : (p == 1) ? qv[j].y : (p == 2) ? qv[j].z : qv[j].w;
                ql[j] = bflo(u); qh[j] = bfhi(u);
            }
#pragma unroll
            for (int r = 0; r < RPW; ++r)
#pragma unroll
                for (int j = 0; j < CPG; ++j)
                    acc[r][j] += wl[r] * ql[j] + wh[r] * qh[j];
        }
    }

    // reduce across the 16 lanes of each group
#pragma unroll
    for (int off = 1; off < 16; off <<= 1)
#pragma unroll
        for (int r = 0; r < RPW; ++r)
#pragma unroll
            for (int j = 0; j < CPG; ++j)
                acc[r][j] += __shfl_xor(acc[r][j], off);

    // gather: lane (g,l) collects sd[e] = seg_diff for (row m0+g, class e)
    float sd[DC];
#pragma unroll
    for (int r = 0; r < RPW; ++r)
#pragma unroll
        for (int e = 0; e < DC; ++e) {
            float t = __shfl(acc[r][e % CPG], (e / CPG) * 16 + l);
            if (g == r) sd[e] = t;
        }

    const int m  = m0 + g;
    const int d1 = l;                 // classes 0..15
    const int d2 = 16 + l;            // classes 16..23 (valid real class iff l<5)

    float u1 = 0.f;
#pragma unroll
    for (int e = 0; e < DC; ++e) u1 += wc[d1 * DC + e] * sd[e];
    float v1 = seg[((size_t)b * DC + d1) * NN + m] - u1;

    float v2 = -INFINITY;
    if (l < 5) {
        float u2 = 0.f;
#pragma unroll
        for (int e = 0; e < DC; ++e) u2 += wc[d2 * DC + e] * sd[e];
        v2 = seg[((size_t)b * DC + d2) * NN + m] - u2;
    }

    if (last) {
        out[((size_t)b * DC + d1) * NN + m] = v1;
        if (l < 5) out[((size_t)b * DC + d2) * NN + m] = v2;
    } else {
        float mx = fmaxf(v1, v2);
#pragma unroll
        for (int off = 1; off < 16; off <<= 1) mx = fmaxf(mx, __shfl_xor(mx, off));
        float e1 = __expf(v1 - mx);
        float e2 = (l < 5) ? __expf(v2 - mx) : 0.f;
        float ss = e1 + e2;
#pragma unroll
        for (int off = 1; off < 16; off <<= 1) ss += __shfl_xor(ss, off);
        float inv = 1.f / ss;
        qnext[((size_t)b * DCP + d1) * NN + m] = f2bf(e1 * inv);
        if (l < 8)
            qnext[((size_t)b * DCP + d2) * NN + m] = (l < 5) ? f2bf(e2 * inv) : (u16)0;
    }
}

// ======== fallback path (fp32, round-2 structure) if ws too small ========
__global__ __launch_bounds__(256) void fb_softmax_k(const float* __restrict__ x,
                                                    float* __restrict__ q) {
    unsigned gid = blockIdx.x * 256u + threadIdx.x;
    unsigned b = gid >> 12, n = gid & 4095u;
    const float* xb = x + (size_t)b * DC * NN + n;
    float v[DC]; float m = -1e30f;
#pragma unroll
    for (int d = 0; d < DC; ++d) { v[d] = xb[(size_t)d * NN]; m = fmaxf(m, v[d]); }
    float s = 0.f;
#pragma unroll
    for (int d = 0; d < DC; ++d) { v[d] = __expf(v[d] - m); s += v[d]; }
    float inv = 1.f / s;
    float* qb = q + (size_t)b * DC * NN + n;
#pragma unroll
    for (int d = 0; d < DC; ++d) qb[(size_t)d * NN] = v[d] * inv;
}

__global__ __launch_bounds__(64) void fb_iter_k(const float* __restrict__ Q,
                                                const float* __restrict__ W,
                                                const float* __restrict__ wc,
                                                const float* __restrict__ seg,
                                                float* __restrict__ qnext,
                                                float* __restrict__ out,
                                                int write_q, int write_out) {
    const int lane = threadIdx.x;
    const int g = lane >> 4, l = lane & 15;
    const int b = blockIdx.x >> 9, rb = blockIdx.x & 511;
    const int m0 = rb * 8 + g * 2;
    const float4* Wr0 = (const float4*)(W + ((size_t)b * NN + m0) * NN + l * 4);
    const float4* Wr1 = (const float4*)(W + ((size_t)b * NN + m0 + 1) * NN + l * 4);
    const float4* Qf4 = (const float4*)(Q + (size_t)b * DC * NN + l * 4);
    float acc0[DC], acc1[DC];
#pragma unroll
    for (int d = 0; d < DC; ++d) { acc0[d] = 0.f; acc1[d] = 0.f; }
    float rs0 = 0.f, rs1 = 0.f;
#pragma unroll 2
    for (int s = 0; s < 64; ++s) {
        float4 wa = Wr0[s * 16], wb = Wr1[s * 16];
        rs0 += (wa.x + wa.y) + (wa.z + wa.w);
        rs1 += (wb.x + wb.y) + (wb.z + wb.w);
#pragma unroll
        for (int d = 0; d < DC; ++d) {
            float4 qv = Qf4[d * 1024 + s * 16];
            acc0[d] += qv.x * wa.x + qv.y * wa.y + qv.z * wa.z + qv.w * wa.w;
            acc1[d] += qv.x * wb.x + qv.y * wb.y + qv.z * wb.z + qv.w * wb.w;
        }
    }
#pragma unroll
    for (int off = 1; off < 16; off <<= 1) {
        rs0 += __shfl_xor(rs0, off); rs1 += __shfl_xor(rs1, off);
#pragma unroll
        for (int d = 0; d < DC; ++d) {
            acc0[d] += __shfl_xor(acc0[d], off);
            acc1[d] += __shfl_xor(acc1[d], off);
        }
    }
    const float inv0 = 1.f / rs0, inv1 = 1.f / rs1;
    const int d1 = l, d2 = l + 16;
    const bool has2 = (d2 < DC);
    float u0a = 0.f, u1a = 0.f, u0b = 0.f, u1b = 0.f;
#pragma unroll
    for (int e = 0; e < DC; ++e) {
        float w1 = wc[d1 * DC + e];
        u0a += w1 * acc0[e]; u1a += w1 * acc1[e];
    }
    if (has2) {
#pragma unroll
        for (int e = 0; e < DC; ++e) {
            float w2 = wc[d2 * DC + e];
            u0b += w2 * acc0[e]; u1b += w2 * acc1[e];
        }
    }
    const size_t base = (size_t)b * DC * NN;
    const size_t i0a = base + (size_t)d1 * NN + m0;
    const size_t i0b = base + (size_t)d2 * NN + m0;
    float v0a = seg[i0a] - u0a * inv0;
    float v1a = seg[i0a + 1] - u1a * inv1;
    float v0b = 0.f, v1b = 0.f;
    if (has2) { v0b = seg[i0b] - u0b * inv0; v1b = seg[i0b + 1] - u1b * inv1; }
    if (write_out) {
        out[i0a] = v0a; out[i0a + 1] = v1a;
        if (has2) { out[i0b] = v0b; out[i0b + 1] = v1b; }
    }
    if (write_q) {
        float mx0 = has2 ? fmaxf(v0a, v0b) : v0a;
        float mx1 = has2 ? fmaxf(v1a, v1b) : v1a;
#pragma unroll
        for (int off = 1; off < 16; off <<= 1) {
            mx0 = fmaxf(mx0, __shfl_xor(mx0, off));
            mx1 = fmaxf(mx1, __shfl_xor(mx1, off));
        }
        float e0a = __expf(v0a - mx0), e1a = __expf(v1a - mx1);
        float e0b = has2 ? __expf(v0b - mx0) : 0.f;
        float e1b = has2 ? __expf(v1b - mx1) : 0.f;
        float s0 = e0a + e0b, s1 = e1a + e1b;
#pragma unroll
        for (int off = 1; off < 16; off <<= 1) {
            s0 += __shfl_xor(s0, off); s1 += __shfl_xor(s1, off);
        }
        float is0 = 1.f / s0, is1 = 1.f / s1;
        qnext[i0a] = e0a * is0; qnext[i0a + 1] = e1a * is1;
        if (has2) { qnext[i0b] = e0b * is0; qnext[i0b + 1] = e1b * is1; }
    }
}

extern "C" void kernel_launch(void* const* d_in, const int* in_sizes, int n_in,
                              void* d_out, int out_size, void* d_ws, size_t ws_size,
                              hipStream_t stream) {
    const float* seg = (const float*)d_in[0];
    const float* W   = (const float*)d_in[1];
    const float* wc  = (const float*)d_in[2];
    float* out = (float*)d_out;

    const size_t needD = (size_t)BS * NN * NN * sizeof(u16);     // 134,217,728
    const size_t needQ = (size_t)BS * DCP * NN * sizeof(u16);    // 786,432

    if (ws_size >= needD + 2 * needQ) {
        u16* Dbf = (u16*)d_ws;
        u16* Qa  = (u16*)((char*)d_ws + needD);
        u16* Qb  = Qa + (size_t)BS * DCP * NN;

        prep_k<<<dim3(BS * NN), dim3(64), 0, stream>>>(W, Dbf);
        softmax0_k<<<dim3(BS * NN / 256), dim3(256), 0, stream>>>(seg, Qa);

        const u16* qin = Qa;
        u16* qout = Qb;
        for (int it = 0; it < 5; ++it) {
            iter_k<<<dim3(BS * NN / RPW), dim3(64), 0, stream>>>(
                qin, Dbf, wc, seg, qout, out, (it == 4) ? 1 : 0);
            const u16* t = qin; qin = qout; qout = (u16*)t;
        }
    } else {
        float* Qa = (float*)d_ws;
        float* Qb = Qa + (size_t)BS * DC * NN;
        fb_softmax_k<<<dim3(BS * NN / 256), dim3(256), 0, stream>>>(seg, Qa);
        const float* qin = Qa;
        float* qout = Qb;
        for (int it = 0; it < 5; ++it) {
            fb_iter_k<<<dim3(2048), dim3(64), 0, stream>>>(
                qin, W, wc, seg, qout, out, (it < 4) ? 1 : 0, (it == 4) ? 1 : 0);
            const float* t = qin; qin = qout; qout = (float*)t;
        }
    }
}

// Round 4
// 618.330 us; speedup vs baseline: 2.3635x; 2.3635x over previous
//
#include <hip/hip_runtime.h>
#include <math.h>

// CRF-RNN mean-field, MI355X.  seg:[4][21][4096] f32, W:[4][4096][4096] f32, wc:[21][21] f32.
// qVals_{t+1}[b,d,m] = seg[b,d,m] - sum_e wc[d,e] * (sum_n Q_t[b,e,n] * D[b,m,n]),
//   D = W / rowsum(W), precomputed ONCE as bf16 (128 MiB, Infinity-Cache resident),
//   Q_t = softmax_d(qVals_t), stored bf16 class-major with 32-class stride.
//
// iter_k: bf16 MFMA tall-skinny GEMM. Block = 256 thr = 4 waves = 4 K-splits of the
// same 16 rows. Per k-step: A-frag = D[m0+r][k..k+8] (lane r=l&15, quad k-run),
// B-lo/B-hi = Q[class][k..k+8] (class = l&15 / 16+(l&15)), all read DIRECTLY from
// global (8 contiguous bf16 = one 16B load = exactly the mfma frag k-run).
// ~70 VGPRs total -> no spill (round-3 failure mode: 568 MB/dispatch scratch traffic).
// C-partials (16x32 f32) reduced across the 4 waves via LDS; epilogue fuses
// compat mix, seg-subtract, and next iteration's softmax.
// Pad classes 21..31 are never written: their C columns are computed from garbage
// but provably never consumed (columns independent; only cols 0..20 read).
// Q ping-pong: buffer A in ws, buffer B aliased onto d_out (dead until last iter).

#define DC 21
#define DCP 32
#define NN 4096
#define BS 4

typedef unsigned int u32;
typedef unsigned short u16;
typedef short s8v __attribute__((ext_vector_type(8)));
typedef float f4v __attribute__((ext_vector_type(4)));

__device__ __forceinline__ u16 f2bf(float f) {
    u32 u = __float_as_uint(f);
    u = u + 0x7fffu + ((u >> 16) & 1u);   // RNE
    return (u16)(u >> 16);
}

// ---- one-time: rowsum + normalize + fp32->bf16 (one wave per W row) ----
__global__ __launch_bounds__(64) void prep_k(const float* __restrict__ W,
                                             u16* __restrict__ D) {
    const int m = blockIdx.x;            // b*4096 + row
    const int l = threadIdx.x;
    const float4* Wr = (const float4*)(W + (size_t)m * NN) + l;
    float4 v[16];
    float s = 0.f;
#pragma unroll
    for (int i = 0; i < 16; ++i) {
        v[i] = Wr[i * 64];
        s += (v[i].x + v[i].y) + (v[i].z + v[i].w);
    }
#pragma unroll
    for (int off = 1; off < 64; off <<= 1) s += __shfl_xor(s, off);
    const float inv = 1.f / s;
    u32* Dr = (u32*)(D + (size_t)m * NN);
#pragma unroll
    for (int i = 0; i < 16; ++i) {
        u32 p0 = (u32)f2bf(v[i].x * inv) | ((u32)f2bf(v[i].y * inv) << 16);
        u32 p1 = (u32)f2bf(v[i].z * inv) | ((u32)f2bf(v[i].w * inv) << 16);
        *(uint2*)(Dr + i * 128 + l * 2) = make_uint2(p0, p1);
    }
}

// ---- initial softmax: seg f32 -> Q bf16 (classes 0..20 only; pads stay garbage) ----
__global__ __launch_bounds__(256) void softmax0_k(const float* __restrict__ x,
                                                  u16* __restrict__ q) {
    unsigned gid = blockIdx.x * 256u + threadIdx.x;
    unsigned b = gid >> 12, n = gid & 4095u;
    const float* xb = x + (size_t)b * DC * NN + n;
    float v[DC];
    float m = -1e30f;
#pragma unroll
    for (int d = 0; d < DC; ++d) { v[d] = xb[(size_t)d * NN]; m = fmaxf(m, v[d]); }
    float s = 0.f;
#pragma unroll
    for (int d = 0; d < DC; ++d) { v[d] = __expf(v[d] - m); s += v[d]; }
    float inv = 1.f / s;
    u16* qb = q + (size_t)b * DCP * NN + n;
#pragma unroll
    for (int d = 0; d < DC; ++d) qb[(size_t)d * NN] = f2bf(v[d] * inv);
}

// ---- main iteration: MFMA K-split GEMM + fused epilogue ----
__global__ __launch_bounds__(256, 4) void iter_k(const u16* __restrict__ Q,
                                                 const u16* __restrict__ D,
                                                 const float* __restrict__ wc,
                                                 const float* __restrict__ seg,
                                                 u16* __restrict__ qnext,
                                                 float* __restrict__ out,
                                                 int last) {
    __shared__ float Cf[4][16][DCP];     // per-wave partial C tiles
    __shared__ float wcs[DC * DC];

    const int tid = threadIdx.x;
    const int w   = tid >> 6;            // wave id = K-split (k in [w*1024, w*1024+1024))
    const int l   = tid & 63;
    const int b   = blockIdx.x >> 8;
    const int m0  = (blockIdx.x & 255) * 16;

    for (int i = tid; i < DC * DC; i += 256) wcs[i] = wc[i];

    const int r = l & 15;                // A row / B class index
    const int q4 = l >> 4;               // quad: k-run offset q4*8
    const u16* Ap = D + ((size_t)b * NN + m0 + r) * NN + w * 1024 + q4 * 8;
    const u16* Bl = Q + ((size_t)b * DCP + r) * NN + w * 1024 + q4 * 8;
    const u16* Bh = Bl + (size_t)16 * NN;

    f4v clo = {0.f, 0.f, 0.f, 0.f};
    f4v chi = {0.f, 0.f, 0.f, 0.f};

#pragma unroll 4
    for (int ks = 0; ks < 32; ++ks) {
        s8v a  = *(const s8v*)(Ap + ks * 32);
        s8v bl = *(const s8v*)(Bl + ks * 32);
        s8v bh = *(const s8v*)(Bh + ks * 32);
        clo = __builtin_amdgcn_mfma_f32_16x16x32_bf16(a, bl, clo, 0, 0, 0);
        chi = __builtin_amdgcn_mfma_f32_16x16x32_bf16(a, bh, chi, 0, 0, 0);
    }

    // dump partial C: lane holds col=l&15 (class), rows q4*4+i
#pragma unroll
    for (int i = 0; i < 4; ++i) {
        Cf[w][q4 * 4 + i][r]      = clo[i];
        Cf[w][q4 * 4 + i][16 + r] = chi[i];
    }
    __syncthreads();

    // epilogue: thread t -> row = t>>4 (0..15), lg = t&15 (16-lane group per row)
    const int row = tid >> 4;
    const int lg  = tid & 15;
    const int m   = m0 + row;

    float sd[24];
#pragma unroll
    for (int j = 0; j < 6; ++j) {
        float4 v = make_float4(0.f, 0.f, 0.f, 0.f);
#pragma unroll
        for (int w2 = 0; w2 < 4; ++w2) {
            float4 c = *(const float4*)&Cf[w2][row][j * 4];
            v.x += c.x; v.y += c.y; v.z += c.z; v.w += c.w;
        }
        sd[j * 4 + 0] = v.x; sd[j * 4 + 1] = v.y;
        sd[j * 4 + 2] = v.z; sd[j * 4 + 3] = v.w;
    }

    const int d1 = lg;                   // classes 0..15
    const int d2 = 16 + lg;              // classes 16..20 valid iff lg<5
    float u1 = 0.f;
#pragma unroll
    for (int e = 0; e < DC; ++e) u1 += wcs[d1 * DC + e] * sd[e];
    float v1 = seg[((size_t)b * DC + d1) * NN + m] - u1;

    float v2 = -INFINITY;
    if (lg < 5) {
        float u2 = 0.f;
#pragma unroll
        for (int e = 0; e < DC; ++e) u2 += wcs[d2 * DC + e] * sd[e];
        v2 = seg[((size_t)b * DC + d2) * NN + m] - u2;
    }

    if (last) {
        out[((size_t)b * DC + d1) * NN + m] = v1;
        if (lg < 5) out[((size_t)b * DC + d2) * NN + m] = v2;
    } else {
        float mx = fmaxf(v1, v2);
#pragma unroll
        for (int off = 1; off < 16; off <<= 1) mx = fmaxf(mx, __shfl_xor(mx, off));
        float e1 = __expf(v1 - mx);
        float e2 = (lg < 5) ? __expf(v2 - mx) : 0.f;
        float ss = e1 + e2;
#pragma unroll
        for (int off = 1; off < 16; off <<= 1) ss += __shfl_xor(ss, off);
        float inv = 1.f / ss;
        qnext[((size_t)b * DCP + d1) * NN + m] = f2bf(e1 * inv);
        if (lg < 5) qnext[((size_t)b * DCP + d2) * NN + m] = f2bf(e2 * inv);
    }
}

// ======== fp32 fallback (round-2 structure) if ws too small ========
__global__ __launch_bounds__(256) void fb_softmax_k(const float* __restrict__ x,
                                                    float* __restrict__ q) {
    unsigned gid = blockIdx.x * 256u + threadIdx.x;
    unsigned b = gid >> 12, n = gid & 4095u;
    const float* xb = x + (size_t)b * DC * NN + n;
    float v[DC]; float m = -1e30f;
#pragma unroll
    for (int d = 0; d < DC; ++d) { v[d] = xb[(size_t)d * NN]; m = fmaxf(m, v[d]); }
    float s = 0.f;
#pragma unroll
    for (int d = 0; d < DC; ++d) { v[d] = __expf(v[d] - m); s += v[d]; }
    float inv = 1.f / s;
    float* qb = q + (size_t)b * DC * NN + n;
#pragma unroll
    for (int d = 0; d < DC; ++d) qb[(size_t)d * NN] = v[d] * inv;
}

__global__ __launch_bounds__(64) void fb_iter_k(const float* __restrict__ Q,
                                                const float* __restrict__ W,
                                                const float* __restrict__ wc,
                                                const float* __restrict__ seg,
                                                float* __restrict__ qnext,
                                                float* __restrict__ out,
                                                int write_q, int write_out) {
    const int lane = threadIdx.x;
    const int g = lane >> 4, l = lane & 15;
    const int b = blockIdx.x >> 9, rb = blockIdx.x & 511;
    const int m0 = rb * 8 + g * 2;
    const float4* Wr0 = (const float4*)(W + ((size_t)b * NN + m0) * NN + l * 4);
    const float4* Wr1 = (const float4*)(W + ((size_t)b * NN + m0 + 1) * NN + l * 4);
    const float4* Qf4 = (const float4*)(Q + (size_t)b * DC * NN + l * 4);
    float acc0[DC], acc1[DC];
#pragma unroll
    for (int d = 0; d < DC; ++d) { acc0[d] = 0.f; acc1[d] = 0.f; }
    float rs0 = 0.f, rs1 = 0.f;
#pragma unroll 2
    for (int s = 0; s < 64; ++s) {
        float4 wa = Wr0[s * 16], wb = Wr1[s * 16];
        rs0 += (wa.x + wa.y) + (wa.z + wa.w);
        rs1 += (wb.x + wb.y) + (wb.z + wb.w);
#pragma unroll
        for (int d = 0; d < DC; ++d) {
            float4 qv = Qf4[d * 1024 + s * 16];
            acc0[d] += qv.x * wa.x + qv.y * wa.y + qv.z * wa.z + qv.w * wa.w;
            acc1[d] += qv.x * wb.x + qv.y * wb.y + qv.z * wb.z + qv.w * wb.w;
        }
    }
#pragma unroll
    for (int off = 1; off < 16; off <<= 1) {
        rs0 += __shfl_xor(rs0, off); rs1 += __shfl_xor(rs1, off);
#pragma unroll
        for (int d = 0; d < DC; ++d) {
            acc0[d] += __shfl_xor(acc0[d], off);
            acc1[d] += __shfl_xor(acc1[d], off);
        }
    }
    const float inv0 = 1.f / rs0, inv1 = 1.f / rs1;
    const int d1 = l, d2 = l + 16;
    const bool has2 = (d2 < DC);
    float u0a = 0.f, u1a = 0.f, u0b = 0.f, u1b = 0.f;
#pragma unroll
    for (int e = 0; e < DC; ++e) {
        float w1 = wc[d1 * DC + e];
        u0a += w1 * acc0[e]; u1a += w1 * acc1[e];
    }
    if (has2) {
#pragma unroll
        for (int e = 0; e < DC; ++e) {
            float w2 = wc[d2 * DC + e];
            u0b += w2 * acc0[e]; u1b += w2 * acc1[e];
        }
    }
    const size_t base = (size_t)b * DC * NN;
    const size_t i0a = base + (size_t)d1 * NN + m0;
    const size_t i0b = base + (size_t)d2 * NN + m0;
    float v0a = seg[i0a] - u0a * inv0;
    float v1a = seg[i0a + 1] - u1a * inv1;
    float v0b = 0.f, v1b = 0.f;
    if (has2) { v0b = seg[i0b] - u0b * inv0; v1b = seg[i0b + 1] - u1b * inv1; }
    if (write_out) {
        out[i0a] = v0a; out[i0a + 1] = v1a;
        if (has2) { out[i0b] = v0b; out[i0b + 1] = v1b; }
    }
    if (write_q) {
        float mx0 = has2 ? fmaxf(v0a, v0b) : v0a;
        float mx1 = has2 ? fmaxf(v1a, v1b) : v1a;
#pragma unroll
        for (int off = 1; off < 16; off <<= 1) {
            mx0 = fmaxf(mx0, __shfl_xor(mx0, off));
            mx1 = fmaxf(mx1, __shfl_xor(mx1, off));
        }
        float e0a = __expf(v0a - mx0), e1a = __expf(v1a - mx1);
        float e0b = has2 ? __expf(v0b - mx0) : 0.f;
        float e1b = has2 ? __expf(v1b - mx1) : 0.f;
        float s0 = e0a + e0b, s1 = e1a + e1b;
#pragma unroll
        for (int off = 1; off < 16; off <<= 1) {
            s0 += __shfl_xor(s0, off); s1 += __shfl_xor(s1, off);
        }
        float is0 = 1.f / s0, is1 = 1.f / s1;
        qnext[i0a] = e0a * is0; qnext[i0a + 1] = e1a * is1;
        if (has2) { qnext[i0b] = e0b * is0; qnext[i0b + 1] = e1b * is1; }
    }
}

extern "C" void kernel_launch(void* const* d_in, const int* in_sizes, int n_in,
                              void* d_out, int out_size, void* d_ws, size_t ws_size,
                              hipStream_t stream) {
    const float* seg = (const float*)d_in[0];
    const float* W   = (const float*)d_in[1];
    const float* wc  = (const float*)d_in[2];
    float* out = (float*)d_out;

    const size_t needD = (size_t)BS * NN * NN * sizeof(u16);      // 134,217,728
    const size_t needQ = (size_t)BS * DCP * NN * sizeof(u16);     // 1,048,576

    if (ws_size >= needD + needQ && (size_t)out_size * sizeof(float) >= needQ) {
        u16* Dbf = (u16*)d_ws;
        u16* Q0  = (u16*)((char*)d_ws + needD);
        u16* Q1  = (u16*)d_out;          // d_out doubles as Q buffer until last iter

        prep_k<<<dim3(BS * NN), dim3(64), 0, stream>>>(W, Dbf);
        softmax0_k<<<dim3(BS * NN / 256), dim3(256), 0, stream>>>(seg, Q0);

        const u16* qin = Q0;
        u16* qout = Q1;
        for (int it = 0; it < 5; ++it) {
            iter_k<<<dim3(BS * NN / 16), dim3(256), 0, stream>>>(
                qin, Dbf, wc, seg, qout, out, (it == 4) ? 1 : 0);
            const u16* t = qin; qin = qout; qout = (u16*)t;
        }
    } else {
        float* Qa = (float*)d_ws;
        float* Qb = Qa + (size_t)BS * DC * NN;
        fb_softmax_k<<<dim3(BS * NN / 256), dim3(256), 0, stream>>>(seg, Qa);
        const float* qin = Qa;
        float* qout = Qb;
        for (int it = 0; it < 5; ++it) {
            fb_iter_k<<<dim3(2048), dim3(64), 0, stream>>>(
                qin, W, wc, seg, qout, out, (it < 4) ? 1 : 0, (it == 4) ? 1 : 0);
            const float* t = qin; qin = qout; qout = (float*)t;
        }
    }
}